// Round 1
// baseline (457.880 us; speedup 1.0000x reference)
//
#include <hip/hip_runtime.h>
#include <hip/hip_bf16.h>

#define B_ 8
#define E_ 1024
#define D_ 256
#define H_ 8
#define NB_ 6
#define HD_ 32
#define EPS_ 1e-5f

// ---------------------------------------------------------------------------
// Generic tiled fp32 GEMM: C = A[M,K] @ W[K,N] + bias[N]
// ACT: 0 = none, 1 = exact GELU.  QKV: 1 = remap store to [B,H,E,HD] layout.
// Block 256 threads, 64x64 tile, BK=16, 4x4 micro-tile per thread.
// ---------------------------------------------------------------------------
template<int ACT, int QKV>
__global__ __launch_bounds__(256) void gemm_k(const float* __restrict__ A,
                                              const float* __restrict__ W,
                                              const float* __restrict__ bias,
                                              float* __restrict__ C,
                                              int M, int N, int K) {
  __shared__ float As[64][17];   // pad 17: conflict-free broadcast reads
  __shared__ float Ws[16][64];
  const int tid = threadIdx.x;
  const int tx = tid & 15, ty = tid >> 4;
  const int row0 = blockIdx.x * 64, col0 = blockIdx.y * 64;
  const int lr = tid >> 2;           // A-load row 0..63
  const int lc = (tid & 3) * 4;      // A-load col 0,4,8,12
  const int wr = tid >> 6;           // W-load row base 0..3
  const int wc = tid & 63;           // W-load col
  float acc[4][4] = {};
  for (int k0 = 0; k0 < K; k0 += 16) {
    float4 av = *(const float4*)(A + (size_t)(row0 + lr) * K + k0 + lc);
    As[lr][lc + 0] = av.x; As[lr][lc + 1] = av.y;
    As[lr][lc + 2] = av.z; As[lr][lc + 3] = av.w;
#pragma unroll
    for (int i = 0; i < 4; i++)
      Ws[wr + i * 4][wc] = W[(size_t)(k0 + wr + i * 4) * N + col0 + wc];
    __syncthreads();
#pragma unroll
    for (int kk = 0; kk < 16; kk++) {
      const float4 bv = *(const float4*)&Ws[kk][tx * 4];
#pragma unroll
      for (int i = 0; i < 4; i++) {
        const float a = As[ty * 4 + i][kk];
        acc[i][0] += a * bv.x; acc[i][1] += a * bv.y;
        acc[i][2] += a * bv.z; acc[i][3] += a * bv.w;
      }
    }
    __syncthreads();
  }
#pragma unroll
  for (int i = 0; i < 4; i++) {
    const int r = row0 + ty * 4 + i;
#pragma unroll
    for (int j = 0; j < 4; j++) {
      const int c = col0 + tx * 4 + j;
      float v = acc[i][j] + bias[c];
      if (ACT == 1) v = 0.5f * v * (1.0f + erff(v * 0.70710678118654752f));
      if (QKV) {
        const int b = r >> 10, e = r & 1023;       // E_ = 1024
        const int h = c >> 5, hd = c & 31;         // HD_ = 32
        C[(((size_t)b * H_ + h) * E_ + e) * HD_ + hd] = v;
      } else {
        C[(size_t)r * N + c] = v;
      }
    }
  }
}

// ---------------------------------------------------------------------------
// Flash-style attention with learned relative bias + key-padding mask.
// Grid: (B*H, E/64). Block 256. Q-tile 64 rows, K-tiles of 64, online softmax.
// ---------------------------------------------------------------------------
__global__ __launch_bounds__(256) void attn_k(const float* __restrict__ q,
                                              const float* __restrict__ k,
                                              const float* __restrict__ v,
                                              const int* __restrict__ rel,
                                              const unsigned char* __restrict__ mask,
                                              const float* __restrict__ bias_emb,
                                              float* __restrict__ out) {
  __shared__ float Qs[64][33];
  __shared__ float Ks[64][33];
  __shared__ float Vs[64][36];        // pad 36 keeps float4 alignment
  __shared__ float S[64][65];
  __shared__ float m_s[64], l_s[64], f_s[64];
  __shared__ float bias_s[NB_];
  __shared__ float msk_s[64];

  const int tid = threadIdx.x;
  const int bh = blockIdx.x;
  const int b = bh >> 3, h = bh & 7;
  const int q0 = blockIdx.y * 64;
  const float scale = 0.17677669529663687f;   // 1/sqrt(32)

  if (tid < NB_) bias_s[tid] = bias_emb[tid * H_ + h];
  if (tid < 64) { m_s[tid] = -INFINITY; l_s[tid] = 0.0f; }

  {  // load Q tile
    const int r = tid >> 2, c0 = (tid & 3) * 8;
    const float* src = q + (((size_t)b * H_ + h) * E_ + q0 + r) * HD_ + c0;
    const float4 x0 = *(const float4*)src;
    const float4 x1 = *(const float4*)(src + 4);
    Qs[r][c0 + 0] = x0.x; Qs[r][c0 + 1] = x0.y; Qs[r][c0 + 2] = x0.z; Qs[r][c0 + 3] = x0.w;
    Qs[r][c0 + 4] = x1.x; Qs[r][c0 + 5] = x1.y; Qs[r][c0 + 6] = x1.z; Qs[r][c0 + 7] = x1.w;
  }

  const int tx = tid & 15, ty = tid >> 4;          // score micro-tile
  const int orow = tid >> 2, oc0 = (tid & 3) * 8;  // O ownership
  const int ln = tid & 63, wv = tid >> 6;
  const int srow = wv * 16 + (ln >> 2), scg = ln & 3;  // softmax ownership
  float o[8] = {};

  for (int kt = 0; kt < 16; kt++) {
    const int k0 = kt * 64;
    {  // load K,V tiles + mask
      const int r = tid >> 2, c0 = (tid & 3) * 8;
      const float* ksrc = k + (((size_t)b * H_ + h) * E_ + k0 + r) * HD_ + c0;
      const float4 k0v = *(const float4*)ksrc;
      const float4 k1v = *(const float4*)(ksrc + 4);
      Ks[r][c0 + 0] = k0v.x; Ks[r][c0 + 1] = k0v.y; Ks[r][c0 + 2] = k0v.z; Ks[r][c0 + 3] = k0v.w;
      Ks[r][c0 + 4] = k1v.x; Ks[r][c0 + 5] = k1v.y; Ks[r][c0 + 6] = k1v.z; Ks[r][c0 + 7] = k1v.w;
      const float* vsrc = v + (((size_t)b * H_ + h) * E_ + k0 + r) * HD_ + c0;
      *(float4*)&Vs[r][c0]     = *(const float4*)vsrc;
      *(float4*)&Vs[r][c0 + 4] = *(const float4*)(vsrc + 4);
      if (tid < 64) msk_s[tid] = mask[b * E_ + k0 + tid] ? -INFINITY : 0.0f;
    }
    __syncthreads();

    // ---- scores: S[64][64] = scale*Q.K^T + bias[rel] + mask ----
    float sacc[4][4] = {};
#pragma unroll 8
    for (int d = 0; d < HD_; d++) {
      float a[4], bb[4];
#pragma unroll
      for (int i = 0; i < 4; i++) a[i] = Qs[ty * 4 + i][d];
#pragma unroll
      for (int j = 0; j < 4; j++) bb[j] = Ks[tx * 4 + j][d];
#pragma unroll
      for (int i = 0; i < 4; i++)
#pragma unroll
        for (int j = 0; j < 4; j++)
          sacc[i][j] += a[i] * bb[j];
    }
#pragma unroll
    for (int i = 0; i < 4; i++) {
      const int r = ty * 4 + i;
      const int4 rr = *(const int4*)(rel + ((size_t)b * E_ + q0 + r) * E_ + k0 + tx * 4);
      S[r][tx * 4 + 0] = sacc[i][0] * scale + bias_s[rr.x] + msk_s[tx * 4 + 0];
      S[r][tx * 4 + 1] = sacc[i][1] * scale + bias_s[rr.y] + msk_s[tx * 4 + 1];
      S[r][tx * 4 + 2] = sacc[i][2] * scale + bias_s[rr.z] + msk_s[tx * 4 + 2];
      S[r][tx * 4 + 3] = sacc[i][3] * scale + bias_s[rr.w] + msk_s[tx * 4 + 3];
    }
    __syncthreads();

    // ---- online softmax update (4 lanes per row) ----
    {
      float vals[16];
      float lm = -INFINITY;
#pragma unroll
      for (int i = 0; i < 16; i++) {
        vals[i] = S[srow][scg * 16 + i];
        lm = fmaxf(lm, vals[i]);
      }
      lm = fmaxf(lm, __shfl_xor(lm, 1));
      lm = fmaxf(lm, __shfl_xor(lm, 2));
      const float mold = m_s[srow];
      const float mn = fmaxf(mold, lm);
      const float msafe = (mn == -INFINITY) ? 0.0f : mn;   // nan_to_num semantics
      float ls = 0.0f;
#pragma unroll
      for (int i = 0; i < 16; i++) {
        const float p = __expf(vals[i] - msafe);           // exp(-inf)=0 for masked
        S[srow][scg * 16 + i] = p;
        ls += p;
      }
      ls += __shfl_xor(ls, 1);
      ls += __shfl_xor(ls, 2);
      if (scg == 0) {
        const float fac = __expf(mold - msafe);            // mold=-inf -> 0
        m_s[srow] = mn;
        f_s[srow] = fac;
        l_s[srow] = fac * l_s[srow] + ls;
      }
    }
    __syncthreads();

    // ---- O += P @ V with rescale ----
    {
      const float fac = f_s[orow];
#pragma unroll
      for (int i = 0; i < 8; i++) o[i] *= fac;
#pragma unroll 8
      for (int j = 0; j < 64; j++) {
        const float pj = S[orow][j];
        const float4 v0 = *(const float4*)&Vs[j][oc0];
        const float4 v1 = *(const float4*)&Vs[j][oc0 + 4];
        o[0] += pj * v0.x; o[1] += pj * v0.y; o[2] += pj * v0.z; o[3] += pj * v0.w;
        o[4] += pj * v1.x; o[5] += pj * v1.y; o[6] += pj * v1.z; o[7] += pj * v1.w;
      }
    }
    __syncthreads();   // protect Vs/S before next tile's loads
  }

  // final normalize + store to [B,E,D]
  const float l = l_s[orow];
  const float inv = (l > 0.0f) ? 1.0f / l : 0.0f;
  float* dst = out + ((size_t)b * E_ + q0 + orow) * D_ + h * HD_ + oc0;
  float4 r0, r1;
  r0.x = o[0] * inv; r0.y = o[1] * inv; r0.z = o[2] * inv; r0.w = o[3] * inv;
  r1.x = o[4] * inv; r1.y = o[5] * inv; r1.z = o[6] * inv; r1.w = o[7] * inv;
  *(float4*)dst = r0;
  *(float4*)(dst + 4) = r1;
}

// ---------------------------------------------------------------------------
// Fused residual-add + LayerNorm over rows of 256. One wave per row.
// ---------------------------------------------------------------------------
__global__ __launch_bounds__(256) void add_ln_k(const float* __restrict__ A,
                                                const float* __restrict__ Bv,
                                                const float* __restrict__ g,
                                                const float* __restrict__ beta,
                                                float* __restrict__ out) {
  const int wv = threadIdx.x >> 6, lane = threadIdx.x & 63;
  const size_t row = (size_t)blockIdx.x * 4 + wv;
  const float4 a4 = *(const float4*)(A + row * D_ + lane * 4);
  const float4 b4 = *(const float4*)(Bv + row * D_ + lane * 4);
  float vv[4] = {a4.x + b4.x, a4.y + b4.y, a4.z + b4.z, a4.w + b4.w};
  float s = vv[0] + vv[1] + vv[2] + vv[3];
#pragma unroll
  for (int off = 1; off < 64; off <<= 1) s += __shfl_xor(s, off);
  const float mu = s * (1.0f / D_);
  float qsum = 0.0f;
#pragma unroll
  for (int i = 0; i < 4; i++) { const float d = vv[i] - mu; qsum += d * d; }
#pragma unroll
  for (int off = 1; off < 64; off <<= 1) qsum += __shfl_xor(qsum, off);
  const float rstd = rsqrtf(qsum * (1.0f / D_) + EPS_);
  const float4 g4 = *(const float4*)(g + lane * 4);
  const float4 be4 = *(const float4*)(beta + lane * 4);
  float4 o4;
  o4.x = (vv[0] - mu) * rstd * g4.x + be4.x;
  o4.y = (vv[1] - mu) * rstd * g4.y + be4.y;
  o4.z = (vv[2] - mu) * rstd * g4.z + be4.z;
  o4.w = (vv[3] - mu) * rstd * g4.w + be4.w;
  *(float4*)(out + row * D_ + lane * 4) = o4;
}

// ---------------------------------------------------------------------------
extern "C" void kernel_launch(void* const* d_in, const int* in_sizes, int n_in,
                              void* d_out, int out_size, void* d_ws, size_t ws_size,
                              hipStream_t stream) {
  const float* x    = (const float*)d_in[0];
  const int*   rel  = (const int*)d_in[1];
  const unsigned char* mask = (const unsigned char*)d_in[2];  // numpy bool = 1 byte
  const float* wq = (const float*)d_in[3];
  const float* bq = (const float*)d_in[4];
  const float* wk = (const float*)d_in[5];
  const float* bk = (const float*)d_in[6];
  const float* wv = (const float*)d_in[7];
  const float* bv = (const float*)d_in[8];
  const float* wo = (const float*)d_in[9];
  const float* bo = (const float*)d_in[10];
  const float* bias_emb = (const float*)d_in[11];
  const float* g1 = (const float*)d_in[12];
  const float* beta1 = (const float*)d_in[13];
  const float* w1 = (const float*)d_in[14];
  const float* b1f = (const float*)d_in[15];
  const float* w2 = (const float*)d_in[16];
  const float* b2f = (const float*)d_in[17];
  const float* g2 = (const float*)d_in[18];
  const float* beta2 = (const float*)d_in[19];
  float* outp = (float*)d_out;

  char* ws = (char*)d_ws;
  float* qb = (float*)(ws + (size_t)0);           // 8 MiB  [B,H,E,HD]
  float* kb = (float*)(ws + ((size_t)8 << 20));   // 8 MiB
  float* vb = (float*)(ws + ((size_t)16 << 20));  // 8 MiB
  float* ao = (float*)(ws + ((size_t)24 << 20));  // 8 MiB  attn out [B,E,D]
  float* h1 = (float*)(ws + ((size_t)32 << 20));  // 8 MiB
  float* ff = (float*)(ws + ((size_t)40 << 20));  // 32 MiB [8192,1024]
  float* tmp  = qb;   // reuse after attention
  float* tmp2 = kb;   // reuse after attention

  const int M = B_ * E_;   // 8192
  dim3 blk(256);

  // QKV projections -> [B,H,E,HD]
  gemm_k<0, 1><<<dim3(M / 64, D_ / 64), blk, 0, stream>>>(x, wq, bq, qb, M, D_, D_);
  gemm_k<0, 1><<<dim3(M / 64, D_ / 64), blk, 0, stream>>>(x, wk, bk, kb, M, D_, D_);
  gemm_k<0, 1><<<dim3(M / 64, D_ / 64), blk, 0, stream>>>(x, wv, bv, vb, M, D_, D_);
  // attention
  attn_k<<<dim3(B_ * H_, E_ / 64), blk, 0, stream>>>(qb, kb, vb, rel, mask, bias_emb, ao);
  // output projection
  gemm_k<0, 0><<<dim3(M / 64, D_ / 64), blk, 0, stream>>>(ao, wo, bo, tmp, M, D_, D_);
  // h1 = LN(x + proj)
  add_ln_k<<<dim3(M / 4), blk, 0, stream>>>(x, tmp, g1, beta1, h1);
  // FFN
  gemm_k<1, 0><<<dim3(M / 64, (4 * D_) / 64), blk, 0, stream>>>(h1, w1, b1f, ff, M, 4 * D_, D_);
  gemm_k<0, 0><<<dim3(M / 64, D_ / 64), blk, 0, stream>>>(ff, w2, b2f, tmp2, M, D_, 4 * D_);
  // out = LN(h1 + ffn)
  add_ln_k<<<dim3(M / 4), blk, 0, stream>>>(h1, tmp2, g2, beta2, outp);
}

// Round 2
// 172.121 us; speedup vs baseline: 2.6602x; 2.6602x over previous
//
#include <hip/hip_runtime.h>
#include <hip/hip_bf16.h>

#define B_ 8
#define E_ 1024
#define D_ 256
#define H_ 8
#define NB_ 6
#define HD_ 32
#define EPS_ 1e-5f

typedef __bf16 bf16x8 __attribute__((ext_vector_type(8)));
typedef float f32x4 __attribute__((ext_vector_type(4)));
typedef unsigned short us4 __attribute__((ext_vector_type(4)));

static __device__ __forceinline__ unsigned short f2bs(float f) {
  __bf16 h = (__bf16)f;
  return __builtin_bit_cast(unsigned short, h);
}

// ---------------------------------------------------------------------------
// Prep: weights fp32 [K][N] -> bf16 [N][K] (transposed); x fp32 -> bf16.
// blocks 0..191: weight transpose tiles (64x64). blocks 192..319: x convert.
// ---------------------------------------------------------------------------
__global__ __launch_bounds__(256) void prep_k(
    const float* __restrict__ wq, const float* __restrict__ wk,
    const float* __restrict__ wv, const float* __restrict__ wo,
    const float* __restrict__ w1, const float* __restrict__ w2,
    const float* __restrict__ x,
    __bf16* __restrict__ wt_qkv, __bf16* __restrict__ wo_t,
    __bf16* __restrict__ w1_t, __bf16* __restrict__ w2_t,
    __bf16* __restrict__ xb) {
  const int bid = blockIdx.x, tid = threadIdx.x;
  if (bid >= 192) {  // x convert: 2M elems over 128 blocks
    const size_t base = (size_t)(bid - 192) * 16384;
#pragma unroll
    for (int i = 0; i < 16; i++) {
      const size_t idx = base + (size_t)tid * 4 + (size_t)i * 1024;
      const float4 v = *(const float4*)(x + idx);
      us4 o; o.x = f2bs(v.x); o.y = f2bs(v.y); o.z = f2bs(v.z); o.w = f2bs(v.w);
      *(us4*)(xb + idx) = o;
    }
    return;
  }
  const float* src; __bf16* dst; int K, N, tIdx;
  if (bid < 64) {
    const int j = bid >> 4; tIdx = bid & 15;
    src = (j == 0) ? wq : (j == 1) ? wk : (j == 2) ? wv : wo;
    dst = (j < 3) ? (wt_qkv + j * 256 * 256) : wo_t;
    K = 256; N = 256;
  } else if (bid < 128) {
    src = w1; dst = w1_t; K = 256; N = 1024; tIdx = bid - 64;
  } else {
    src = w2; dst = w2_t; K = 1024; N = 256; tIdx = bid - 128;
  }
  const int ntn = N / 64;
  const int k0 = (tIdx / ntn) * 64, n0 = (tIdx % ntn) * 64;
  __shared__ __align__(16) float ts[64][68];
  {
    const int r = tid >> 2, c0 = (tid & 3) * 16;
#pragma unroll
    for (int i = 0; i < 4; i++) {
      const float4 v = *(const float4*)(src + (size_t)(k0 + r) * N + n0 + c0 + i * 4);
      *(float4*)&ts[r][c0 + i * 4] = v;
    }
  }
  __syncthreads();
#pragma unroll
  for (int i = 0; i < 2; i++) {
    const int cid = tid * 2 + i;            // 0..511
    const int n = cid >> 3, kc = (cid & 7) * 8;
    unsigned int u[4];
#pragma unroll
    for (int j = 0; j < 4; j++) {
      const unsigned int lo = f2bs(ts[kc + 2 * j][n]);
      const unsigned int hi = f2bs(ts[kc + 2 * j + 1][n]);
      u[j] = lo | (hi << 16);
    }
    uint4 o; o.x = u[0]; o.y = u[1]; o.z = u[2]; o.w = u[3];
    *(uint4*)(dst + (size_t)(n0 + n) * K + k0 + kc) = o;
  }
}

// ---------------------------------------------------------------------------
// Unified bf16 MFMA GEMM:  D[n][e] = sum_k Wt[n][k] * Act[e][k]  (+bias[n])
// Tile 64n x 128e, BK=64, 256 threads (4 waves as 2n x 2e).
// MODE 0: fp32 out [e][N].  MODE 1: gelu -> bf16 out [e][N].
// MODE 2: QK heads -> outh=[B,H,E,32] (n<256), outh2 likewise (n>=256).
// MODE 3: SWAP orientation, V^T -> outh=[B,H,32,E].
// ---------------------------------------------------------------------------
template<int MODE>
__global__ __launch_bounds__(256) void gemm_k(
    const __bf16* __restrict__ Wt, const __bf16* __restrict__ Act,
    const float* __restrict__ bias0, const float* __restrict__ bias1,
    float* __restrict__ outf, __bf16* __restrict__ outh,
    __bf16* __restrict__ outh2, int N, int K) {
  constexpr bool SWAP = (MODE == 3);
  __shared__ __align__(16) char lds[24576];  // Wl 8KB [64][64] + Al 16KB [128][64]
  const int tid = threadIdx.x;
  const int l = tid & 63, w = tid >> 6;
  const int lr = l & 15, lg = l >> 4;
  const int wn = w >> 1, we = w & 1;
  const int n0 = blockIdx.x * 64, e0 = blockIdx.y * 128;
  f32x4 acc[8] = {};
  const int nk = K >> 6;
  for (int ks = 0; ks < nk; ks++) {
    const int k0 = ks << 6;
    if (ks) __syncthreads();
#pragma unroll
    for (int i = 0; i < 2; i++) {  // stage Wt tile
      const int f = tid + i * 256; const int r = f >> 3, c = f & 7;
      const bf16x8 v = *(const bf16x8*)(Wt + (size_t)(n0 + r) * K + k0 + c * 8);
      *(bf16x8*)(lds + r * 128 + ((c ^ (r & 7)) * 16)) = v;
    }
#pragma unroll
    for (int i = 0; i < 4; i++) {  // stage Act tile
      const int f = tid + i * 256; const int r = f >> 3, c = f & 7;
      const bf16x8 v = *(const bf16x8*)(Act + (size_t)(e0 + r) * K + k0 + c * 8);
      *(bf16x8*)(lds + 8192 + r * 128 + ((c ^ (r & 7)) * 16)) = v;
    }
    __syncthreads();
#pragma unroll
    for (int s = 0; s < 2; s++) {
      bf16x8 wf[2], af[4];
#pragma unroll
      for (int nf = 0; nf < 2; nf++) {
        const int row = wn * 32 + nf * 16 + lr;
        wf[nf] = *(const bf16x8*)(lds + row * 128 + (((s * 4 + lg) ^ (row & 7)) * 16));
      }
#pragma unroll
      for (int ef = 0; ef < 4; ef++) {
        const int row = we * 64 + ef * 16 + lr;
        af[ef] = *(const bf16x8*)(lds + 8192 + row * 128 + (((s * 4 + lg) ^ (row & 7)) * 16));
      }
#pragma unroll
      for (int nf = 0; nf < 2; nf++)
#pragma unroll
        for (int ef = 0; ef < 4; ef++) {
          if constexpr (!SWAP)
            acc[nf * 4 + ef] = __builtin_amdgcn_mfma_f32_16x16x32_bf16(wf[nf], af[ef], acc[nf * 4 + ef], 0, 0, 0);
          else
            acc[ef * 2 + nf] = __builtin_amdgcn_mfma_f32_16x16x32_bf16(af[ef], wf[nf], acc[ef * 2 + nf], 0, 0, 0);
        }
    }
  }
  // ---- epilogue ----
  if constexpr (!SWAP) {
#pragma unroll
    for (int nf = 0; nf < 2; nf++) {
      const int n_first = n0 + wn * 32 + nf * 16 + 4 * lg;
#pragma unroll
      for (int ef = 0; ef < 4; ef++) {
        const int e = e0 + we * 64 + ef * 16 + lr;
        f32x4 v = acc[nf * 4 + ef];
        if constexpr (MODE == 0 || MODE == 1) {
          const f32x4 b4 = *(const f32x4*)(bias0 + n_first);
          v += b4;
          if constexpr (MODE == 0) {
            *(f32x4*)(outf + (size_t)e * N + n_first) = v;
          } else {
            us4 o;
#pragma unroll
            for (int r = 0; r < 4; r++) {
              const float g = 0.5f * v[r] * (1.0f + erff(v[r] * 0.70710678118654752f));
              if (r == 0) o.x = f2bs(g); else if (r == 1) o.y = f2bs(g);
              else if (r == 2) o.z = f2bs(g); else o.w = f2bs(g);
            }
            *(us4*)(outh + (size_t)e * N + n_first) = o;
          }
        } else {  // MODE 2: QK
          const float* bp = (n_first < 256) ? bias0 : bias1;
          const int nn = n_first & 255;
          const f32x4 b4 = *(const f32x4*)(bp + nn);
          v += b4;
          __bf16* dstb = (n_first < 256) ? outh : outh2;
          const int h = nn >> 5, hd = nn & 31;
          const int b = e >> 10, ee = e & 1023;
          us4 o; o.x = f2bs(v[0]); o.y = f2bs(v[1]); o.z = f2bs(v[2]); o.w = f2bs(v[3]);
          *(us4*)(dstb + (((size_t)(b * 8 + h) * 1024 + ee) * 32) + hd) = o;
        }
      }
    }
  } else {  // MODE 3: V^T store [B,H,32,E]
#pragma unroll
    for (int ef = 0; ef < 4; ef++) {
      const int e_first = e0 + we * 64 + ef * 16 + 4 * lg;
#pragma unroll
      for (int nf = 0; nf < 2; nf++) {
        const int n = n0 + wn * 32 + nf * 16 + lr;
        f32x4 v = acc[ef * 2 + nf];
        const float bs = bias0[n];
        v += bs;
        const int h = n >> 5, hd = n & 31;
        const int b = e_first >> 10, ee = e_first & 1023;
        us4 o; o.x = f2bs(v[0]); o.y = f2bs(v[1]); o.z = f2bs(v[2]); o.w = f2bs(v[3]);
        *(us4*)(outh + (((size_t)(b * 8 + h) * 32 + hd) * 1024) + ee) = o;
      }
    }
  }
}

// ---------------------------------------------------------------------------
// MFMA flash attention. Grid 256 = (b, q-tile of 32). 8 waves = 8 heads.
// S^T = K·Q^T per 64-key tile; rel staged as u8 in LDS (shared by heads);
// K/V fragments straight from global (L2-hot, no cross-wave reuse);
// P via per-wave swizzled LDS tile; O accumulated transposed.
// ---------------------------------------------------------------------------
__global__ __launch_bounds__(512) void attn_k(
    const __bf16* __restrict__ qb, const __bf16* __restrict__ kb,
    const __bf16* __restrict__ vt, const int* __restrict__ rel,
    const unsigned char* __restrict__ mask, const float* __restrict__ bias_emb,
    __bf16* __restrict__ ao) {
  __shared__ unsigned char rel8[32][68];
  __shared__ float msk_s[64];
  __shared__ __align__(16) __bf16 P_lds[8][32 * 64];
  const int tid = threadIdx.x;
  const int l = tid & 63, w = tid >> 6;     // w = head
  const int lr = l & 15, lg = l >> 4;
  const int bid = blockIdx.x;
  const int b = bid >> 5, q0 = (bid & 31) * 32;
  const float scale = 0.17677669529663687f;  // 1/sqrt(32)

  float bb[6];
#pragma unroll
  for (int i = 0; i < 6; i++) bb[i] = bias_emb[i * 8 + w];

  bf16x8 qf[2];
#pragma unroll
  for (int nf = 0; nf < 2; nf++)
    qf[nf] = *(const bf16x8*)(qb + ((size_t)(b * 8 + w) * 1024 + q0 + 16 * nf + lr) * 32 + 8 * lg);

  f32x4 acc_o[2][2] = {};
  float m_run[2] = {-INFINITY, -INFINITY};
  float l_run[2] = {0.0f, 0.0f};
  const __bf16* Kbase = kb + (size_t)(b * 8 + w) * 1024 * 32;
  const __bf16* Vbase = vt + (size_t)(b * 8 + w) * 32 * 1024;
  char* Pl = (char*)&P_lds[w][0];

  for (int kt = 0; kt < 16; kt++) {
    const int k0 = kt * 64;
    __syncthreads();
    {  // stage rel tile [32 q][64 k] as u8
      const int r = tid >> 4, c = tid & 15;
      const int4 rv = *(const int4*)(rel + ((size_t)b * 1024 + q0 + r) * 1024 + k0 + c * 4);
      const unsigned int packed = (unsigned)rv.x | ((unsigned)rv.y << 8) |
                                  ((unsigned)rv.z << 16) | ((unsigned)rv.w << 24);
      *(unsigned int*)&rel8[r][c * 4] = packed;
    }
    if (tid < 64) msk_s[tid] = mask[b * 1024 + k0 + tid] ? -INFINITY : 0.0f;
    __syncthreads();

    // ---- S^T = K · Q^T ----
    f32x4 s_acc[4][2] = {};
#pragma unroll
    for (int mf = 0; mf < 4; mf++) {
      const bf16x8 kf = *(const bf16x8*)(Kbase + (size_t)(k0 + 16 * mf + lr) * 32 + 8 * lg);
#pragma unroll
      for (int nf = 0; nf < 2; nf++)
        s_acc[mf][nf] = __builtin_amdgcn_mfma_f32_16x16x32_bf16(kf, qf[nf], s_acc[mf][nf], 0, 0, 0);
    }

    // ---- scale + bias[rel] + mask, row(=q) max over k ----
    float mt[2] = {-INFINITY, -INFINITY};
#pragma unroll
    for (int mf = 0; mf < 4; mf++) {
      float mk[4];
      const f32x4 mk4 = *(const f32x4*)&msk_s[16 * mf + 4 * lg];
      mk[0] = mk4[0]; mk[1] = mk4[1]; mk[2] = mk4[2]; mk[3] = mk4[3];
#pragma unroll
      for (int nf = 0; nf < 2; nf++) {
        const unsigned int rr = *(const unsigned int*)&rel8[16 * nf + lr][16 * mf + 4 * lg];
#pragma unroll
        for (int r = 0; r < 4; r++) {
          const int idx = (rr >> (8 * r)) & 255;
          const float bs = (idx == 0) ? bb[0] : (idx == 1) ? bb[1] : (idx == 2) ? bb[2]
                         : (idx == 3) ? bb[3] : (idx == 4) ? bb[4] : bb[5];
          const float sv = s_acc[mf][nf][r] * scale + bs + mk[r];
          s_acc[mf][nf][r] = sv;
          mt[nf] = fmaxf(mt[nf], sv);
        }
      }
    }
#pragma unroll
    for (int nf = 0; nf < 2; nf++) {
      mt[nf] = fmaxf(mt[nf], __shfl_xor(mt[nf], 16));
      mt[nf] = fmaxf(mt[nf], __shfl_xor(mt[nf], 32));
      const float mn = fmaxf(m_run[nf], mt[nf]);
      const float msafe = (mn == -INFINITY) ? 0.0f : mn;
      const float alpha = __expf(m_run[nf] - msafe);
      m_run[nf] = mn;
      float ls = 0.0f;
#pragma unroll
      for (int mf = 0; mf < 4; mf++)
#pragma unroll
        for (int r = 0; r < 4; r++) {
          const float e = __expf(s_acc[mf][nf][r] - msafe);
          s_acc[mf][nf][r] = e;
          ls += e;
        }
      ls += __shfl_xor(ls, 16);
      ls += __shfl_xor(ls, 32);
      l_run[nf] = l_run[nf] * alpha + ls;
      acc_o[0][nf] *= alpha;
      acc_o[1][nf] *= alpha;
    }

    // ---- P -> LDS (bf16, swizzled rows of 128B) ----
#pragma unroll
    for (int nf = 0; nf < 2; nf++) {
      const int q = 16 * nf + lr;
      char* rowp = Pl + q * 128;
#pragma unroll
      for (int mf = 0; mf < 4; mf++) {
        us4 pv;
        pv.x = f2bs(s_acc[mf][nf][0]); pv.y = f2bs(s_acc[mf][nf][1]);
        pv.z = f2bs(s_acc[mf][nf][2]); pv.w = f2bs(s_acc[mf][nf][3]);
        *(us4*)(rowp + ((32 * mf + 8 * lg) ^ ((q & 7) << 4))) = pv;
      }
    }

    // ---- O^T += V^T · P^T ----
#pragma unroll
    for (int s = 0; s < 2; s++) {
      bf16x8 pf[2];
#pragma unroll
      for (int nf = 0; nf < 2; nf++) {
        const int q = 16 * nf + lr;
        pf[nf] = *(const bf16x8*)(Pl + q * 128 + ((64 * s + 16 * lg) ^ ((q & 7) << 4)));
      }
#pragma unroll
      for (int m2 = 0; m2 < 2; m2++) {
        const bf16x8 vf = *(const bf16x8*)(Vbase + (size_t)(16 * m2 + lr) * 1024 + k0 + 32 * s + 8 * lg);
#pragma unroll
        for (int nf = 0; nf < 2; nf++)
          acc_o[m2][nf] = __builtin_amdgcn_mfma_f32_16x16x32_bf16(vf, pf[nf], acc_o[m2][nf], 0, 0, 0);
      }
    }
  }

  // ---- normalize + store bf16 [B,E,256] ----
#pragma unroll
  for (int nf = 0; nf < 2; nf++) {
    const float lv = l_run[nf];
    const float inv = (lv > 0.0f) ? 1.0f / lv : 0.0f;
    const int q = 16 * nf + lr;
#pragma unroll
    for (int m2 = 0; m2 < 2; m2++) {
      us4 o;
      o.x = f2bs(acc_o[m2][nf][0] * inv); o.y = f2bs(acc_o[m2][nf][1] * inv);
      o.z = f2bs(acc_o[m2][nf][2] * inv); o.w = f2bs(acc_o[m2][nf][3] * inv);
      *(us4*)(ao + ((size_t)b * 1024 + q0 + q) * 256 + w * 32 + 16 * m2 + 4 * lg) = o;
    }
  }
}

// ---------------------------------------------------------------------------
// Fused residual-add + LayerNorm (one wave per 256-row). WB: also bf16 copy.
// ---------------------------------------------------------------------------
template<bool WB>
__global__ __launch_bounds__(256) void add_ln_k(const float* __restrict__ A,
                                                const float* __restrict__ Bv,
                                                const float* __restrict__ g,
                                                const float* __restrict__ beta,
                                                float* __restrict__ out,
                                                __bf16* __restrict__ outb) {
  const int wv = threadIdx.x >> 6, lane = threadIdx.x & 63;
  const size_t row = (size_t)blockIdx.x * 4 + wv;
  const float4 a4 = *(const float4*)(A + row * D_ + lane * 4);
  const float4 b4 = *(const float4*)(Bv + row * D_ + lane * 4);
  float vv[4] = {a4.x + b4.x, a4.y + b4.y, a4.z + b4.z, a4.w + b4.w};
  float s = vv[0] + vv[1] + vv[2] + vv[3];
#pragma unroll
  for (int off = 1; off < 64; off <<= 1) s += __shfl_xor(s, off);
  const float mu = s * (1.0f / D_);
  float qsum = 0.0f;
#pragma unroll
  for (int i = 0; i < 4; i++) { const float d = vv[i] - mu; qsum += d * d; }
#pragma unroll
  for (int off = 1; off < 64; off <<= 1) qsum += __shfl_xor(qsum, off);
  const float rstd = rsqrtf(qsum * (1.0f / D_) + EPS_);
  const float4 g4 = *(const float4*)(g + lane * 4);
  const float4 be4 = *(const float4*)(beta + lane * 4);
  float4 o4;
  o4.x = (vv[0] - mu) * rstd * g4.x + be4.x;
  o4.y = (vv[1] - mu) * rstd * g4.y + be4.y;
  o4.z = (vv[2] - mu) * rstd * g4.z + be4.z;
  o4.w = (vv[3] - mu) * rstd * g4.w + be4.w;
  *(float4*)(out + row * D_ + lane * 4) = o4;
  if constexpr (WB) {
    us4 o; o.x = f2bs(o4.x); o.y = f2bs(o4.y); o.z = f2bs(o4.z); o.w = f2bs(o4.w);
    *(us4*)(outb + row * D_ + lane * 4) = o;
  }
}

// ---------------------------------------------------------------------------
extern "C" void kernel_launch(void* const* d_in, const int* in_sizes, int n_in,
                              void* d_out, int out_size, void* d_ws, size_t ws_size,
                              hipStream_t stream) {
  const float* x    = (const float*)d_in[0];
  const int*   rel  = (const int*)d_in[1];
  const unsigned char* mask = (const unsigned char*)d_in[2];
  const float* wq = (const float*)d_in[3];
  const float* bq = (const float*)d_in[4];
  const float* wk = (const float*)d_in[5];
  const float* bk = (const float*)d_in[6];
  const float* wv = (const float*)d_in[7];
  const float* bv = (const float*)d_in[8];
  const float* wo = (const float*)d_in[9];
  const float* bo = (const float*)d_in[10];
  const float* bias_emb = (const float*)d_in[11];
  const float* g1 = (const float*)d_in[12];
  const float* beta1 = (const float*)d_in[13];
  const float* w1 = (const float*)d_in[14];
  const float* b1f = (const float*)d_in[15];
  const float* w2 = (const float*)d_in[16];
  const float* b2f = (const float*)d_in[17];
  const float* g2 = (const float*)d_in[18];
  const float* beta2 = (const float*)d_in[19];
  float* outp = (float*)d_out;

  char* ws = (char*)d_ws;
  __bf16* wt_qkv = (__bf16*)(ws + 0);             // 384 KB [768][256]
  __bf16* wo_t   = (__bf16*)(ws + 393216);        // 128 KB
  __bf16* w1_t   = (__bf16*)(ws + 524288);        // 512 KB [1024][256]
  __bf16* w2_t   = (__bf16*)(ws + 1048576);       // 512 KB [256][1024]
  __bf16* xb     = (__bf16*)(ws + 1572864);       // 4 MB
  __bf16* qbuf   = (__bf16*)(ws + 5767168);       // 4 MB [B,H,E,32]
  __bf16* kbuf   = (__bf16*)(ws + 9961472);       // 4 MB
  __bf16* vtb    = (__bf16*)(ws + 14155776);      // 4 MB [B,H,32,E]
  __bf16* ao     = (__bf16*)(ws + 18350080);      // 4 MB [B,E,256]
  float*  tmp    = (float*)(ws + 22544384);       // 8 MB
  float*  h1     = (float*)(ws + 30932992);       // 8 MB
  __bf16* h1b    = (__bf16*)(ws + 39321600);      // 4 MB
  __bf16* ffb    = (__bf16*)(ws + 43515904);      // 16 MB [8192][1024]
  float*  tmp2   = (float*)(ws + 60293120);       // 8 MB

  dim3 blk(256);
  prep_k<<<dim3(320), blk, 0, stream>>>(wq, wk, wv, wo, w1, w2, x,
                                        wt_qkv, wo_t, w1_t, w2_t, xb);
  // Q,K projections (fused, N=512)
  gemm_k<2><<<dim3(8, 64), blk, 0, stream>>>(wt_qkv, xb, bq, bk,
                                             nullptr, qbuf, kbuf, 512, 256);
  // V projection, transposed store
  gemm_k<3><<<dim3(4, 64), blk, 0, stream>>>(wt_qkv + 512 * 256, xb, bv, nullptr,
                                             nullptr, vtb, nullptr, 256, 256);
  // attention
  attn_k<<<dim3(256), dim3(512), 0, stream>>>(qbuf, kbuf, vtb, rel, mask, bias_emb, ao);
  // output projection (fp32 out)
  gemm_k<0><<<dim3(4, 64), blk, 0, stream>>>(wo_t, ao, bo, nullptr,
                                             tmp, nullptr, nullptr, 256, 256);
  // h1 = LN(x + proj), fp32 + bf16
  add_ln_k<true><<<dim3(2048), blk, 0, stream>>>(x, tmp, g1, beta1, h1, h1b);
  // FFN1 (gelu, bf16 out)
  gemm_k<1><<<dim3(16, 64), blk, 0, stream>>>(w1_t, h1b, b1f, nullptr,
                                              nullptr, ffb, nullptr, 1024, 256);
  // FFN2 (fp32 out)
  gemm_k<0><<<dim3(4, 64), blk, 0, stream>>>(w2_t, ffb, b2f, nullptr,
                                             tmp2, nullptr, nullptr, 256, 1024);
  // out = LN(h1 + ffn)
  add_ln_k<false><<<dim3(2048), blk, 0, stream>>>(h1, tmp2, g2, beta2, outp, nullptr);
}

// Round 3
// 159.930 us; speedup vs baseline: 2.8630x; 1.0762x over previous
//
#include <hip/hip_runtime.h>
#include <hip/hip_bf16.h>

#define B_ 8
#define E_ 1024
#define D_ 256
#define H_ 8
#define NB_ 6
#define HD_ 32
#define EPS_ 1e-5f

typedef __bf16 bf16x8 __attribute__((ext_vector_type(8)));
typedef float f32x4 __attribute__((ext_vector_type(4)));
typedef unsigned short us4 __attribute__((ext_vector_type(4)));

#define LOG2E_ 1.4426950408889634f
#define C_QS_ (0.17677669529663687f * 1.4426950408889634f)  // scale * log2e

static __device__ __forceinline__ unsigned short f2bs(float f) {
  __bf16 h = (__bf16)f;
  return __builtin_bit_cast(unsigned short, h);
}

// ---------------------------------------------------------------------------
// Prep: weights fp32 [K][N] -> bf16 [N][K] (transposed; wq pre-scaled by
// scale*log2e); x fp32 -> bf16; rel8m[b,q,k] = mask[b,k] ? 6 : rel[b,q,k].
// blocks 0..191 weights, 192..319 x convert, 320..575 rel8m.
// ---------------------------------------------------------------------------
__global__ __launch_bounds__(256) void prep_k(
    const float* __restrict__ wq, const float* __restrict__ wk,
    const float* __restrict__ wv, const float* __restrict__ wo,
    const float* __restrict__ w1, const float* __restrict__ w2,
    const float* __restrict__ x,
    const int* __restrict__ rel, const unsigned char* __restrict__ mask,
    __bf16* __restrict__ wt_qkv, __bf16* __restrict__ wo_t,
    __bf16* __restrict__ w1_t, __bf16* __restrict__ w2_t,
    __bf16* __restrict__ xb, unsigned char* __restrict__ rel8m) {
  const int bid = blockIdx.x, tid = threadIdx.x;
  if (bid >= 320) {  // rel8m fold: 256 blocks, 32 rows each
    const int r = bid - 320;
    const int b = r >> 5, rg = r & 31;
    const int row = rg * 32 + (tid >> 3);
    const int c0 = (tid & 7) * 128;
    const int* rp = rel + ((size_t)b * 1024 + row) * 1024 + c0;
    const unsigned char* mp = mask + b * 1024 + c0;
    unsigned char* op = rel8m + ((size_t)b * 1024 + row) * 1024 + c0;
#pragma unroll
    for (int i = 0; i < 8; i++) {
      const uint4 mb = *(const uint4*)(mp + i * 16);
      unsigned mw[4] = {mb.x, mb.y, mb.z, mb.w};
      unsigned out[4];
#pragma unroll
      for (int j = 0; j < 4; j++) {
        const int4 rv = *(const int4*)(rp + i * 16 + j * 4);
        const unsigned m = mw[j];
        unsigned v;
        v  = ((m & 0xFFu)       ? 6u : (unsigned)rv.x);
        v |= ((m & 0xFF00u)     ? 6u : (unsigned)rv.y) << 8;
        v |= ((m & 0xFF0000u)   ? 6u : (unsigned)rv.z) << 16;
        v |= ((m & 0xFF000000u) ? 6u : (unsigned)rv.w) << 24;
        out[j] = v;
      }
      uint4 o; o.x = out[0]; o.y = out[1]; o.z = out[2]; o.w = out[3];
      *(uint4*)(op + i * 16) = o;
    }
    return;
  }
  if (bid >= 192) {  // x convert
    const size_t base = (size_t)(bid - 192) * 16384;
#pragma unroll
    for (int i = 0; i < 16; i++) {
      const size_t idx = base + (size_t)tid * 4 + (size_t)i * 1024;
      const float4 v = *(const float4*)(x + idx);
      us4 o; o.x = f2bs(v.x); o.y = f2bs(v.y); o.z = f2bs(v.z); o.w = f2bs(v.w);
      *(us4*)(xb + idx) = o;
    }
    return;
  }
  const float* src; __bf16* dst; int K, N, tIdx;
  if (bid < 64) {
    const int j = bid >> 4; tIdx = bid & 15;
    src = (j == 0) ? wq : (j == 1) ? wk : (j == 2) ? wv : wo;
    dst = (j < 3) ? (wt_qkv + j * 256 * 256) : wo_t;
    K = 256; N = 256;
  } else if (bid < 128) {
    src = w1; dst = w1_t; K = 256; N = 1024; tIdx = bid - 64;
  } else {
    src = w2; dst = w2_t; K = 1024; N = 256; tIdx = bid - 128;
  }
  const float mul = (bid < 16) ? C_QS_ : 1.0f;   // wq tiles pre-scaled
  const int ntn = N / 64;
  const int k0 = (tIdx / ntn) * 64, n0 = (tIdx % ntn) * 64;
  __shared__ __align__(16) float ts[64][68];
  {
    const int r = tid >> 2, c0 = (tid & 3) * 16;
#pragma unroll
    for (int i = 0; i < 4; i++) {
      const float4 v = *(const float4*)(src + (size_t)(k0 + r) * N + n0 + c0 + i * 4);
      *(float4*)&ts[r][c0 + i * 4] = v;
    }
  }
  __syncthreads();
#pragma unroll
  for (int i = 0; i < 2; i++) {
    const int cid = tid * 2 + i;
    const int n = cid >> 3, kc = (cid & 7) * 8;
    unsigned int u[4];
#pragma unroll
    for (int j = 0; j < 4; j++) {
      const unsigned int lo = f2bs(ts[kc + 2 * j][n] * mul);
      const unsigned int hi = f2bs(ts[kc + 2 * j + 1][n] * mul);
      u[j] = lo | (hi << 16);
    }
    uint4 o; o.x = u[0]; o.y = u[1]; o.z = u[2]; o.w = u[3];
    *(uint4*)(dst + (size_t)(n0 + n) * K + k0 + kc) = o;
  }
}

// ---------------------------------------------------------------------------
// Unified bf16 MFMA GEMM (unchanged except MODE 2 Q-bias pre-scale).
// ---------------------------------------------------------------------------
template<int MODE>
__global__ __launch_bounds__(256) void gemm_k(
    const __bf16* __restrict__ Wt, const __bf16* __restrict__ Act,
    const float* __restrict__ bias0, const float* __restrict__ bias1,
    float* __restrict__ outf, __bf16* __restrict__ outh,
    __bf16* __restrict__ outh2, int N, int K) {
  constexpr bool SWAP = (MODE == 3);
  __shared__ __align__(16) char lds[24576];
  const int tid = threadIdx.x;
  const int l = tid & 63, w = tid >> 6;
  const int lr = l & 15, lg = l >> 4;
  const int wn = w >> 1, we = w & 1;
  const int n0 = blockIdx.x * 64, e0 = blockIdx.y * 128;
  f32x4 acc[8] = {};
  const int nk = K >> 6;
  for (int ks = 0; ks < nk; ks++) {
    const int k0 = ks << 6;
    if (ks) __syncthreads();
#pragma unroll
    for (int i = 0; i < 2; i++) {
      const int f = tid + i * 256; const int r = f >> 3, c = f & 7;
      const bf16x8 v = *(const bf16x8*)(Wt + (size_t)(n0 + r) * K + k0 + c * 8);
      *(bf16x8*)(lds + r * 128 + ((c ^ (r & 7)) * 16)) = v;
    }
#pragma unroll
    for (int i = 0; i < 4; i++) {
      const int f = tid + i * 256; const int r = f >> 3, c = f & 7;
      const bf16x8 v = *(const bf16x8*)(Act + (size_t)(e0 + r) * K + k0 + c * 8);
      *(bf16x8*)(lds + 8192 + r * 128 + ((c ^ (r & 7)) * 16)) = v;
    }
    __syncthreads();
#pragma unroll
    for (int s = 0; s < 2; s++) {
      bf16x8 wf[2], af[4];
#pragma unroll
      for (int nf = 0; nf < 2; nf++) {
        const int row = wn * 32 + nf * 16 + lr;
        wf[nf] = *(const bf16x8*)(lds + row * 128 + (((s * 4 + lg) ^ (row & 7)) * 16));
      }
#pragma unroll
      for (int ef = 0; ef < 4; ef++) {
        const int row = we * 64 + ef * 16 + lr;
        af[ef] = *(const bf16x8*)(lds + 8192 + row * 128 + (((s * 4 + lg) ^ (row & 7)) * 16));
      }
#pragma unroll
      for (int nf = 0; nf < 2; nf++)
#pragma unroll
        for (int ef = 0; ef < 4; ef++) {
          if constexpr (!SWAP)
            acc[nf * 4 + ef] = __builtin_amdgcn_mfma_f32_16x16x32_bf16(wf[nf], af[ef], acc[nf * 4 + ef], 0, 0, 0);
          else
            acc[ef * 2 + nf] = __builtin_amdgcn_mfma_f32_16x16x32_bf16(af[ef], wf[nf], acc[ef * 2 + nf], 0, 0, 0);
        }
    }
  }
  if constexpr (!SWAP) {
#pragma unroll
    for (int nf = 0; nf < 2; nf++) {
      const int n_first = n0 + wn * 32 + nf * 16 + 4 * lg;
#pragma unroll
      for (int ef = 0; ef < 4; ef++) {
        const int e = e0 + we * 64 + ef * 16 + lr;
        f32x4 v = acc[nf * 4 + ef];
        if constexpr (MODE == 0 || MODE == 1) {
          const f32x4 b4 = *(const f32x4*)(bias0 + n_first);
          v += b4;
          if constexpr (MODE == 0) {
            *(f32x4*)(outf + (size_t)e * N + n_first) = v;
          } else {
            us4 o;
#pragma unroll
            for (int r = 0; r < 4; r++) {
              const float g = 0.5f * v[r] * (1.0f + erff(v[r] * 0.70710678118654752f));
              if (r == 0) o.x = f2bs(g); else if (r == 1) o.y = f2bs(g);
              else if (r == 2) o.z = f2bs(g); else o.w = f2bs(g);
            }
            *(us4*)(outh + (size_t)e * N + n_first) = o;
          }
        } else {  // MODE 2: QK heads
          const float* bp = (n_first < 256) ? bias0 : bias1;
          const int nn = n_first & 255;
          f32x4 b4 = *(const f32x4*)(bp + nn);
          if (n_first < 256) b4 *= C_QS_;       // Q bias pre-scaled
          v += b4;
          __bf16* dstb = (n_first < 256) ? outh : outh2;
          const int h = nn >> 5, hd = nn & 31;
          const int b = e >> 10, ee = e & 1023;
          us4 o; o.x = f2bs(v[0]); o.y = f2bs(v[1]); o.z = f2bs(v[2]); o.w = f2bs(v[3]);
          *(us4*)(dstb + (((size_t)(b * 8 + h) * 1024 + ee) * 32) + hd) = o;
        }
      }
    }
  } else {  // MODE 3: V^T store [B,H,32,E]
#pragma unroll
    for (int ef = 0; ef < 4; ef++) {
      const int e_first = e0 + we * 64 + ef * 16 + 4 * lg;
#pragma unroll
      for (int nf = 0; nf < 2; nf++) {
        const int n = n0 + wn * 32 + nf * 16 + lr;
        f32x4 v = acc[ef * 2 + nf];
        const float bs = bias0[n];
        v += bs;
        const int h = n >> 5, hd = n & 31;
        const int b = e_first >> 10, ee = e_first & 1023;
        us4 o; o.x = f2bs(v[0]); o.y = f2bs(v[1]); o.z = f2bs(v[2]); o.w = f2bs(v[3]);
        *(us4*)(outh + (((size_t)(b * 8 + h) * 32 + hd) * 1024) + ee) = o;
      }
    }
  }
}

// ---------------------------------------------------------------------------
// Barrier-free MFMA flash attention, exp2 domain.
// Grid 1024 blocks x 256 thr (4 waves). wave = (b, h, 16-row q-tile).
// b = bid&7 (XCD-local L2 working set). Per-wave LDS: P tile + bias table.
// K-frags + rel u32s double-buffered (named regs), V issued before softmax.
// ---------------------------------------------------------------------------
__global__ __launch_bounds__(256, 4) void attn_k(
    const __bf16* __restrict__ qb,   // [B,H,E,32], pre-scaled by scale*log2e
    const __bf16* __restrict__ kb,   // [B,H,E,32]
    const __bf16* __restrict__ vt,   // [B,H,32,E]
    const unsigned char* __restrict__ rel8m,  // [B,E,E], mask folded as 6
    const float* __restrict__ bias_emb,
    __bf16* __restrict__ ao) {
  __shared__ __align__(16) __bf16 P_lds[4][16 * 64];
  __shared__ float tbl[4][8];
  const int tid = threadIdx.x;
  const int l = tid & 63, w = tid >> 6;
  const int lr = l & 15, lg = l >> 4;
  const int bid = blockIdx.x;
  const int b = bid & 7;
  const int rest = bid >> 3;
  const int hg = rest & 1, qt = rest >> 1;
  const int h = hg * 4 + w;
  const int q0 = qt * 16;

  if (l < 8)
    tbl[w][l] = (l < 6) ? bias_emb[l * 8 + h] * LOG2E_ : -INFINITY;
  const float* twp = &tbl[w][0];

  const __bf16* Kb = kb + (size_t)(b * 8 + h) * (1024 * 32);
  const __bf16* Vb = vt + (size_t)(b * 8 + h) * (32 * 1024);
  const unsigned char* Rrow = rel8m + ((size_t)b * 1024 + q0 + lr) * 1024 + 4 * lg;
  char* Pw = (char*)&P_lds[w][0];
  const int psw = (lr & 7) << 4;

  const bf16x8 qf = *(const bf16x8*)(qb + ((size_t)(b * 8 + h) * 1024 + q0 + lr) * 32 + 8 * lg);

  f32x4 acc0 = {}, acc1 = {};
  float m_run = -INFINITY, l_run = 0.0f;

  bf16x8 kfA[4], kfB[4];
  unsigned rrA[4], rrB[4];
#pragma unroll
  for (int mf = 0; mf < 4; mf++) {
    kfA[mf] = *(const bf16x8*)(Kb + (size_t)(16 * mf + lr) * 32 + 8 * lg);
    rrA[mf] = *(const unsigned*)(Rrow + 16 * mf);
  }

  auto tile = [&](bf16x8 (&kf)[4], unsigned (&rr)[4],
                  bf16x8 (&kfN)[4], unsigned (&rrN)[4], int k0) {
    // ---- S^T = K · Qs^T (exp2 domain) ----
    f32x4 s[4];
#pragma unroll
    for (int mf = 0; mf < 4; mf++) {
      f32x4 z = {};
      s[mf] = __builtin_amdgcn_mfma_f32_16x16x32_bf16(kf[mf], qf, z, 0, 0, 0);
    }
    // ---- prefetch next tile's K + rel (wraps harmlessly at end) ----
    const int kN = (k0 + 64) & 1023;
#pragma unroll
    for (int mf = 0; mf < 4; mf++) {
      kfN[mf] = *(const bf16x8*)(Kb + (size_t)(kN + 16 * mf + lr) * 32 + 8 * lg);
      rrN[mf] = *(const unsigned*)(Rrow + kN + 16 * mf);
    }
    // ---- issue V loads early (consumed after softmax) ----
    bf16x8 vf[2][2];
#pragma unroll
    for (int m2 = 0; m2 < 2; m2++)
#pragma unroll
      for (int s2 = 0; s2 < 2; s2++)
        vf[m2][s2] = *(const bf16x8*)(Vb + (size_t)(16 * m2 + lr) * 1024 + k0 + 32 * s2 + 8 * lg);
    // ---- bias gather (LDS, conflict-free) + row max ----
    float mt = -INFINITY;
#pragma unroll
    for (int mf = 0; mf < 4; mf++)
#pragma unroll
      for (int r = 0; r < 4; r++) {
        const int idx = (rr[mf] >> (8 * r)) & 255;
        const float sv = s[mf][r] + twp[idx];
        s[mf][r] = sv;
        mt = fmaxf(mt, sv);
      }
    mt = fmaxf(mt, __shfl_xor(mt, 16));
    mt = fmaxf(mt, __shfl_xor(mt, 32));
    const float mn = fmaxf(m_run, mt);
    const float msafe = (mn == -INFINITY) ? 0.0f : mn;
    const float alpha = exp2f(m_run - msafe);
    m_run = mn;
    float ls = 0.0f;
#pragma unroll
    for (int mf = 0; mf < 4; mf++)
#pragma unroll
      for (int r = 0; r < 4; r++) {
        const float p = exp2f(s[mf][r] - msafe);
        s[mf][r] = p;
        ls += p;
      }
    ls += __shfl_xor(ls, 16);
    ls += __shfl_xor(ls, 32);
    l_run = l_run * alpha + ls;
    acc0 *= alpha; acc1 *= alpha;
    // ---- P -> per-wave LDS (swizzled), then PV ----
#pragma unroll
    for (int mf = 0; mf < 4; mf++) {
      us4 pv;
      pv.x = f2bs(s[mf][0]); pv.y = f2bs(s[mf][1]);
      pv.z = f2bs(s[mf][2]); pv.w = f2bs(s[mf][3]);
      *(us4*)(Pw + lr * 128 + ((32 * mf + 8 * lg) ^ psw)) = pv;
    }
#pragma unroll
    for (int s2 = 0; s2 < 2; s2++) {
      const bf16x8 pf = *(const bf16x8*)(Pw + lr * 128 + ((64 * s2 + 16 * lg) ^ psw));
      acc0 = __builtin_amdgcn_mfma_f32_16x16x32_bf16(vf[0][s2], pf, acc0, 0, 0, 0);
      acc1 = __builtin_amdgcn_mfma_f32_16x16x32_bf16(vf[1][s2], pf, acc1, 0, 0, 0);
    }
  };

#pragma unroll 1
  for (int p = 0; p < 8; p++) {
    tile(kfA, rrA, kfB, rrB, p * 128);
    tile(kfB, rrB, kfA, rrA, p * 128 + 64);
  }

  // ---- normalize + store bf16 [B,E,256] ----
  const float inv = (l_run > 0.0f) ? 1.0f / l_run : 0.0f;
  {
    us4 o;
    o.x = f2bs(acc0[0] * inv); o.y = f2bs(acc0[1] * inv);
    o.z = f2bs(acc0[2] * inv); o.w = f2bs(acc0[3] * inv);
    *(us4*)(ao + ((size_t)b * 1024 + q0 + lr) * 256 + h * 32 + 4 * lg) = o;
    o.x = f2bs(acc1[0] * inv); o.y = f2bs(acc1[1] * inv);
    o.z = f2bs(acc1[2] * inv); o.w = f2bs(acc1[3] * inv);
    *(us4*)(ao + ((size_t)b * 1024 + q0 + lr) * 256 + h * 32 + 16 + 4 * lg) = o;
  }
}

// ---------------------------------------------------------------------------
// Fused residual-add + LayerNorm (one wave per 256-row). WB: also bf16 copy.
// ---------------------------------------------------------------------------
template<bool WB>
__global__ __launch_bounds__(256) void add_ln_k(const float* __restrict__ A,
                                                const float* __restrict__ Bv,
                                                const float* __restrict__ g,
                                                const float* __restrict__ beta,
                                                float* __restrict__ out,
                                                __bf16* __restrict__ outb) {
  const int wv = threadIdx.x >> 6, lane = threadIdx.x & 63;
  const size_t row = (size_t)blockIdx.x * 4 + wv;
  const float4 a4 = *(const float4*)(A + row * D_ + lane * 4);
  const float4 b4 = *(const float4*)(Bv + row * D_ + lane * 4);
  float vv[4] = {a4.x + b4.x, a4.y + b4.y, a4.z + b4.z, a4.w + b4.w};
  float s = vv[0] + vv[1] + vv[2] + vv[3];
#pragma unroll
  for (int off = 1; off < 64; off <<= 1) s += __shfl_xor(s, off);
  const float mu = s * (1.0f / D_);
  float qsum = 0.0f;
#pragma unroll
  for (int i = 0; i < 4; i++) { const float d = vv[i] - mu; qsum += d * d; }
#pragma unroll
  for (int off = 1; off < 64; off <<= 1) qsum += __shfl_xor(qsum, off);
  const float rstd = rsqrtf(qsum * (1.0f / D_) + EPS_);
  const float4 g4 = *(const float4*)(g + lane * 4);
  const float4 be4 = *(const float4*)(beta + lane * 4);
  float4 o4;
  o4.x = (vv[0] - mu) * rstd * g4.x + be4.x;
  o4.y = (vv[1] - mu) * rstd * g4.y + be4.y;
  o4.z = (vv[2] - mu) * rstd * g4.z + be4.z;
  o4.w = (vv[3] - mu) * rstd * g4.w + be4.w;
  *(float4*)(out + row * D_ + lane * 4) = o4;
  if constexpr (WB) {
    us4 o; o.x = f2bs(o4.x); o.y = f2bs(o4.y); o.z = f2bs(o4.z); o.w = f2bs(o4.w);
    *(us4*)(outb + row * D_ + lane * 4) = o;
  }
}

// ---------------------------------------------------------------------------
extern "C" void kernel_launch(void* const* d_in, const int* in_sizes, int n_in,
                              void* d_out, int out_size, void* d_ws, size_t ws_size,
                              hipStream_t stream) {
  const float* x    = (const float*)d_in[0];
  const int*   rel  = (const int*)d_in[1];
  const unsigned char* mask = (const unsigned char*)d_in[2];
  const float* wq = (const float*)d_in[3];
  const float* bq = (const float*)d_in[4];
  const float* wk = (const float*)d_in[5];
  const float* bk = (const float*)d_in[6];
  const float* wv = (const float*)d_in[7];
  const float* bv = (const float*)d_in[8];
  const float* wo = (const float*)d_in[9];
  const float* bo = (const float*)d_in[10];
  const float* bias_emb = (const float*)d_in[11];
  const float* g1 = (const float*)d_in[12];
  const float* beta1 = (const float*)d_in[13];
  const float* w1 = (const float*)d_in[14];
  const float* b1f = (const float*)d_in[15];
  const float* w2 = (const float*)d_in[16];
  const float* b2f = (const float*)d_in[17];
  const float* g2 = (const float*)d_in[18];
  const float* beta2 = (const float*)d_in[19];
  float* outp = (float*)d_out;

  char* ws = (char*)d_ws;
  __bf16* wt_qkv = (__bf16*)(ws + 0);             // 384 KB [768][256]
  __bf16* wo_t   = (__bf16*)(ws + 393216);        // 128 KB
  __bf16* w1_t   = (__bf16*)(ws + 524288);        // 512 KB
  __bf16* w2_t   = (__bf16*)(ws + 1048576);       // 512 KB
  __bf16* xb     = (__bf16*)(ws + 1572864);       // 4 MB
  __bf16* qbuf   = (__bf16*)(ws + 5767168);       // 4 MB [B,H,E,32]
  __bf16* kbuf   = (__bf16*)(ws + 9961472);       // 4 MB
  __bf16* vtb    = (__bf16*)(ws + 14155776);      // 4 MB [B,H,32,E]
  __bf16* ao     = (__bf16*)(ws + 18350080);      // 4 MB [B,E,256]
  float*  tmp    = (float*)(ws + 22544384);       // 8 MB
  float*  h1     = (float*)(ws + 30932992);       // 8 MB
  __bf16* h1b    = (__bf16*)(ws + 39321600);      // 4 MB
  __bf16* ffb    = (__bf16*)(ws + 43515904);      // 16 MB (FFN phase)
  unsigned char* rel8m = (unsigned char*)(ws + 43515904);  // 8 MB (attn phase, disjoint lifetime)
  float*  tmp2   = (float*)(ws + 60293120);       // 8 MB

  dim3 blk(256);
  prep_k<<<dim3(576), blk, 0, stream>>>(wq, wk, wv, wo, w1, w2, x, rel, mask,
                                        wt_qkv, wo_t, w1_t, w2_t, xb, rel8m);
  // Q,K projections (fused, N=512); Q side pre-scaled by scale*log2e
  gemm_k<2><<<dim3(8, 64), blk, 0, stream>>>(wt_qkv, xb, bq, bk,
                                             nullptr, qbuf, kbuf, 512, 256);
  // V projection, transposed store
  gemm_k<3><<<dim3(4, 64), blk, 0, stream>>>(wt_qkv + 512 * 256, xb, bv, nullptr,
                                             nullptr, vtb, nullptr, 256, 256);
  // attention (barrier-free)
  attn_k<<<dim3(1024), blk, 0, stream>>>(qbuf, kbuf, vtb, rel8m, bias_emb, ao);
  // output projection (fp32 out)
  gemm_k<0><<<dim3(4, 64), blk, 0, stream>>>(wo_t, ao, bo, nullptr,
                                             tmp, nullptr, nullptr, 256, 256);
  // h1 = LN(x + proj)
  add_ln_k<true><<<dim3(2048), blk, 0, stream>>>(x, tmp, g1, beta1, h1, h1b);
  // FFN1 (gelu, bf16 out)
  gemm_k<1><<<dim3(16, 64), blk, 0, stream>>>(w1_t, h1b, b1f, nullptr,
                                              nullptr, ffb, nullptr, 1024, 256);
  // FFN2 (fp32 out)
  gemm_k<0><<<dim3(4, 64), blk, 0, stream>>>(w2_t, ffb, b2f, nullptr,
                                             tmp2, nullptr, nullptr, 256, 1024);
  // out = LN(h1 + ffn)
  add_ln_k<false><<<dim3(2048), blk, 0, stream>>>(h1, tmp2, g2, beta2, outp, nullptr);
}